// Round 18
// baseline (55.898 us; speedup 1.0000x reference)
//
#include <hip/hip_runtime.h>

typedef __attribute__((ext_vector_type(8))) short bf16x8;
typedef __attribute__((ext_vector_type(16))) float f32x16;
typedef unsigned int u32;
typedef unsigned short u16;

#define GA   2048     // chunks / scatter WGs; 2048 edges each at E=4.2M
#define NBKT 128      // buckets; bucket = 64 consecutive blocks
#define BATCH 2048    // edges per chunk (single batch per WG)
#define CAPC 64       // u16 slots per (chunk,bucket): 4x mean(16); P(ovf)~2e-18
#define NCPY 4        // countB chunk-split copies

union BF8 { bf16x8 v; u16 u[8]; u32 w[4]; };

static __device__ __forceinline__ u16 f2bf(float f) {
    u32 u = __float_as_uint(f);
    return (u16)((u + 0x7FFFu + ((u >> 16) & 1u)) >> 16);   // RNE
}
// packed 2xf32 -> 2xbf16 in ONE instruction (lo in low half)
static __device__ __forceinline__ u32 f2bf2(float lo, float hi) {
    u32 r;
    asm("v_cvt_pk_bf16_f32 %0, %1, %2" : "=v"(r) : "v"(lo), "v"(hi));
    return r;
}
// branchless fast tanh: 8 VALU ops, |err| ~1e-6 (inputs here are |x| <~ 20)
static __device__ __forceinline__ float tanh_fast(float x) {
    float xc = fminf(fmaxf(x, -15.f), 15.f);
    float t = __expf(2.f * xc);
    return (t - 1.f) * __builtin_amdgcn_rcpf(t + 1.f);
}

// ===========================================================================
// Pass 1: compaction scatter into STATIC per-(chunk,bucket) slots.
// Round-12 structure; single change: 2048 half-size chunks (8 WGs/CU, not 4)
// so the serial {rank -> scan -> stage -> flush} chain of one WG overlaps
// another's. ebuf total unchanged: 2048 x 64 slots = 1024 x 128 re-tiled.
// ===========================================================================
__global__ __launch_bounds__(256) void scatterA(
    const int* __restrict__ row, const int* __restrict__ col,
    u32* __restrict__ count, u16* __restrict__ ebuf, int E, int CH)
{
    __shared__ u32 bcnt[NBKT], bpos[NBKT];
    __shared__ u32 stage[BATCH];
    __shared__ u32 w0s;
    const int t = threadIdx.x, g = blockIdx.x;

    const int beg = g * CH, end = min(E, beg + CH);
    const int nE = end - beg;                       // multiple of 4 (or 0)
    const int4* r4 = reinterpret_cast<const int4*>(row + beg);
    const int4* c4 = reinterpret_cast<const int4*>(col + beg);

    if (t < NBKT) bcnt[t] = 0;
    __syncthreads();

    u32 code[8];
    int rank[8];
    #pragma unroll
    for (int kv = 0; kv < 2; ++kv) {
        int i4 = kv * 256 + t;
        bool v = (i4 * 4) < nE;
        int4 r = v ? r4[i4] : make_int4(0, 0, 0, 0);
        int4 c = v ? c4[i4] : make_int4(0, 0, 0, 0);
        int k0 = kv * 4;
        code[k0 + 0] = v ? (u32)(((r.x >> 5) << 10) | ((r.x & 31) << 5) | (c.x & 31)) : ~0u;
        code[k0 + 1] = v ? (u32)(((r.y >> 5) << 10) | ((r.y & 31) << 5) | (c.y & 31)) : ~0u;
        code[k0 + 2] = v ? (u32)(((r.z >> 5) << 10) | ((r.z & 31) << 5) | (c.z & 31)) : ~0u;
        code[k0 + 3] = v ? (u32)(((r.w >> 5) << 10) | ((r.w & 31) << 5) | (c.w & 31)) : ~0u;
    }
    #pragma unroll
    for (int k = 0; k < 8; ++k)
        rank[k] = (code[k] != ~0u) ? (int)atomicAdd(&bcnt[code[k] >> 16], 1u) : 0;
    __syncthreads();

    // exclusive scan of bcnt over 128 buckets; emit clamped counts
    u32 v_ = (t < NBKT) ? bcnt[t] : 0;
    u32 s = v_;
    #pragma unroll
    for (int off = 1; off < 64; off <<= 1) {
        u32 u_ = __shfl_up(s, off, 64);
        if ((t & 63) >= off) s += u_;
    }
    if (t == 63) w0s = s;
    __syncthreads();
    if (t < NBKT) {
        bpos[t] = s - v_ + ((t >= 64) ? w0s : 0);
        count[g * NBKT + t] = (v_ > CAPC) ? (u32)CAPC : v_;   // coalesced 512 B
    }
    __syncthreads();

    #pragma unroll
    for (int k = 0; k < 8; ++k)
        if (code[k] != ~0u) stage[bpos[code[k] >> 16] + rank[k]] = code[k];
    __syncthreads();

    for (int j = t; j < nE; j += 256) {
        u32 cv = stage[j];
        u32 b = cv >> 16;
        u32 idx = (u32)j - bpos[b];
        if (idx < CAPC)                                   // ~never taken
            ebuf[((size_t)b << 17) + ((u32)g << 6) + idx] = (u16)cv;   // run-contiguous
    }
}

// ===========================================================================
// Pass 2: full-bucket nibble-count adjacency, 4-way chunk split (512 WGs).
// Round-12 structure re-tiled for 2048 chunks x 64 slots; CAPC=64 == wave
// width so the overflow tail path is statically impossible (dropped).
// Output: adj[(bucket*4+q)][8192 u32] — igmc sums the four copies.
// ===========================================================================
__global__ __launch_bounds__(1024) void countB(
    const u16* __restrict__ ebuf, const u32* __restrict__ count, u32* __restrict__ adj)
{
    __shared__ u32 nib[8192];    // 64 blocks x 128 words = 32 KB
    const int t = threadIdx.x, w = blockIdx.x;
    const int bucket = w >> 2;
    const int g0h = (w & 3) * 512;

    #pragma unroll
    for (int i = t; i < 8192; i += 1024) nib[i] = 0;
    __syncthreads();

    const int wave = t >> 6, lane = t & 63;
    const int g0 = g0h + wave * 32;                 // 16 waves x 32 chunks
    u32 mycnt = (lane < 32) ? count[(g0 + lane) * NBKT + bucket] : 0;
    const u32 base = ((u32)bucket << 17);

    #pragma unroll 4
    for (int it = 0; it < 32; ++it) {
        u32 cnt = (u32)__shfl((int)mycnt, it, 64);  // wave-uniform
        u32 sb = base + ((u32)(g0 + it) << 6);
        u32 lc = ebuf[sb + lane];                   // unconditional, coalesced 128B
        if ((u32)lane < cnt)                        // cnt <= 64 == wave width
            atomicAdd(&nib[lc >> 3], 1u << ((lc & 7) << 2));
    }
    __syncthreads();
    u32* dst = adj + (size_t)w * 8192;
    #pragma unroll
    for (int i = t; i < 8192; i += 1024) dst[i] = nib[i];
}

// ===========================================================================
// Kernel 3: 4 subgraphs per 256-thread WG (one wave each), MFMA 32x32x16 bf16.
// (byte-identical to round 17 — measured-equal-best)
//   A-frag (assumed): row = l&31, k = 16f + 8*(l>>5) + i
//   B-frag (assumed): col = l&31, k = 16f + 8*(l>>5) + i
//   C/D   (verified): col = l&31, row = (q&3) + 8*(q>>2) + 4*(l>>5)
// ===========================================================================
__global__ __launch_bounds__(256, 6) void igmc_kernel(
    const float4* __restrict__ feats4,
    const u32* __restrict__ adj, int NB,
    const float* __restrict__ W1, const float* __restrict__ B1,
    const float* __restrict__ W2, const float* __restrict__ B2,
    const float* __restrict__ W3, const float* __restrict__ B3,
    const float* __restrict__ lin1W, const float* __restrict__ lin1b,
    const float* __restrict__ lin2W, const float* __restrict__ lin2b,
    float* __restrict__ out)
{
    __shared__ u32 raw[4][128];                       // nibble count words
    __shared__ __align__(16) u16 Tb[4][2][32 * 36];   // bf16 transpose buffers
    __shared__ float nsL[4][32];
    __shared__ __align__(16) float4 fst[4][32];       // feats staging
    __shared__ float repL[4][192];

    const int tid = threadIdx.x;
    const int w = tid >> 6, l = tid & 63, h = l >> 5, c = l & 31;
    const int b = blockIdx.x * 4 + w;
    const bool valid = (b < NB);

    if (valid) {
        const u32* a0 = adj + (size_t)(b >> 6) * (8192 * NCPY) + (size_t)(b & 63) * 128;
        uint2 r0 = *reinterpret_cast<const uint2*>(a0 + 2 * l);
        uint2 r1 = *reinterpret_cast<const uint2*>(a0 + 8192 + 2 * l);
        uint2 r2 = *reinterpret_cast<const uint2*>(a0 + 16384 + 2 * l);
        uint2 r3 = *reinterpret_cast<const uint2*>(a0 + 24576 + 2 * l);
        uint2 rw;
        rw.x = r0.x + r1.x + r2.x + r3.x;             // nibble-wise add, no carry
        rw.y = r0.y + r1.y + r2.y + r3.y;
        *reinterpret_cast<uint2*>(&raw[w][2 * l]) = rw;
        if (h == 0) fst[w][c] = feats4[(size_t)b * 32 + c];
    }
    __syncthreads();

    float cf[16];
    int colsum = 0;
    #pragma unroll
    for (int f = 0; f < 2; ++f)
        #pragma unroll
        for (int i = 0; i < 8; ++i) {
            int u = 16 * f + 8 * h + i;
            u32 word = raw[w][u * 4 + (c >> 3)];
            int v = (word >> ((c & 7) << 2)) & 15;
            cf[f * 8 + i] = (float)v;
            colsum += v;
        }
    colsum += __shfl_xor(colsum, 32, 64);
    const float ndr = rsqrtf(fmaxf((float)colsum, 1.f));

    if (h == 0) {
        u32 r0 = raw[w][4 * c], r1 = raw[w][4 * c + 1];
        u32 r2 = raw[w][4 * c + 2], r3 = raw[w][4 * c + 3];
        const u32 m = 0x0F0F0F0Fu;
        u32 bs = (r0 & m) + ((r0 >> 4) & m) + (r1 & m) + ((r1 >> 4) & m)
               + (r2 & m) + ((r2 >> 4) & m) + (r3 & m) + ((r3 >> 4) & m);
        u32 p2 = (bs & 0x00FF00FFu) + ((bs >> 8) & 0x00FF00FFu);
        u32 s = (p2 + (p2 >> 16)) & 0xFFFFu;
        nsL[w][c] = rsqrtf(fmaxf((float)s, 1.f));
    }
    __syncthreads();

    BF8 Mf[2];
    #pragma unroll
    for (int f = 0; f < 2; ++f)
        #pragma unroll
        for (int j = 0; j < 4; ++j) {
            int u0 = 16 * f + 8 * h + 2 * j;
            Mf[f].w[j] = f2bf2(cf[f * 8 + 2 * j]     * nsL[w][u0]     * ndr,
                               cf[f * 8 + 2 * j + 1] * nsL[w][u0 + 1] * ndr);
        }

    float w1r0 = W1[c], w1r1 = W1[32 + c], w1r2 = W1[64 + c], w1r3 = W1[96 + c];
    const float b1r = B1[c], b2r = B2[c], b3r = B3[c];
    BF8 W2f[2], W3f[2];
    #pragma unroll
    for (int f = 0; f < 2; ++f)
        #pragma unroll
        for (int j = 0; j < 4; ++j) {
            int k0 = 16 * f + 8 * h + 2 * j;
            W2f[f].w[j] = f2bf2(W2[k0 * 32 + c], W2[(k0 + 1) * 32 + c]);
            W3f[f].w[j] = f2bf2(W3[k0 * 32 + c], W3[(k0 + 1) * 32 + c]);
        }

    BF8 Xa, Xb;
    #pragma unroll
    for (int f = 0; f < 2; ++f)
        #pragma unroll
        for (int j = 0; j < 4; ++j) {
            int u0 = 16 * f + 8 * h + 2 * j;
            float4 x0 = fst[w][u0];
            float4 x1 = fst[w][u0 + 1];
            u32 pk = f2bf2(x0.x * w1r0 + x0.y * w1r1 + x0.z * w1r2 + x0.w * w1r3,
                           x1.x * w1r0 + x1.y * w1r1 + x1.z * w1r2 + x1.w * w1r3);
            if (f == 0) Xa.w[j] = pk; else Xb.w[j] = pk;
        }

    f32x16 acc;
    float th[16];
    u32 p[8], q[8];

    auto zero_acc = [&]() {
        #pragma unroll
        for (int j = 0; j < 16; ++j) acc[j] = 0.f;
    };
    auto pack_exchange = [&](BF8& Ra, BF8& Rb) {
        #pragma unroll
        for (int j = 0; j < 8; ++j) p[j] = f2bf2(th[2 * j], th[2 * j + 1]);
        #pragma unroll
        for (int j = 0; j < 8; ++j) q[j] = __shfl_xor((int)p[j], 32, 64);
        Ra.w[0] = h ? q[2] : p[0];  Ra.w[1] = h ? q[3] : p[1];
        Ra.w[2] = h ? p[2] : q[0];  Ra.w[3] = h ? p[3] : q[1];
        Rb.w[0] = h ? q[6] : p[4];  Rb.w[1] = h ? q[7] : p[5];
        Rb.w[2] = h ? p[6] : q[4];  Rb.w[3] = h ? p[7] : q[5];
    };

    // ==================== Layer 1 ====================
    zero_acc();
    acc = __builtin_amdgcn_mfma_f32_32x32x16_bf16(Mf[0].v, Xa.v, acc, 0, 0, 0);
    acc = __builtin_amdgcn_mfma_f32_32x32x16_bf16(Mf[1].v, Xb.v, acc, 0, 0, 0);
    #pragma unroll
    for (int j = 0; j < 16; ++j) th[j] = tanh_fast(acc[j] + b1r);
    if (h == 0) { repL[w][c] = th[0]; repL[w][96 + c] = th[8]; }
    pack_exchange(Xa, Xb);

    // ==================== Layer 2 ====================
    zero_acc();
    acc = __builtin_amdgcn_mfma_f32_32x32x16_bf16(Mf[0].v, Xa.v, acc, 0, 0, 0);
    acc = __builtin_amdgcn_mfma_f32_32x32x16_bf16(Mf[1].v, Xb.v, acc, 0, 0, 0);
    #pragma unroll
    for (int j = 0; j < 16; ++j) {
        int r = (j & 3) + 8 * (j >> 2) + 4 * h;
        Tb[w][0][r * 36 + c] = f2bf(acc[j]);
    }
    __syncthreads();
    {
        const u32* t32 = reinterpret_cast<const u32*>(&Tb[w][0][0]);
        int base = 18 * c + 4 * h;
        Xa.w[0] = t32[base];     Xa.w[1] = t32[base + 1];
        Xa.w[2] = t32[base + 2]; Xa.w[3] = t32[base + 3];
        Xb.w[0] = t32[base + 8]; Xb.w[1] = t32[base + 9];
        Xb.w[2] = t32[base + 10]; Xb.w[3] = t32[base + 11];
    }
    zero_acc();
    acc = __builtin_amdgcn_mfma_f32_32x32x16_bf16(Xa.v, W2f[0].v, acc, 0, 0, 0);
    acc = __builtin_amdgcn_mfma_f32_32x32x16_bf16(Xb.v, W2f[1].v, acc, 0, 0, 0);
    #pragma unroll
    for (int j = 0; j < 16; ++j) th[j] = tanh_fast(acc[j] + b2r);
    if (h == 0) { repL[w][32 + c] = th[0]; repL[w][128 + c] = th[8]; }
    pack_exchange(Xa, Xb);

    // ==================== Layer 3 ====================
    zero_acc();
    acc = __builtin_amdgcn_mfma_f32_32x32x16_bf16(Mf[0].v, Xa.v, acc, 0, 0, 0);
    acc = __builtin_amdgcn_mfma_f32_32x32x16_bf16(Mf[1].v, Xb.v, acc, 0, 0, 0);
    #pragma unroll
    for (int j = 0; j < 16; ++j) {
        int r = (j & 3) + 8 * (j >> 2) + 4 * h;
        Tb[w][1][r * 36 + c] = f2bf(acc[j]);
    }
    __syncthreads();
    {
        const u32* t32 = reinterpret_cast<const u32*>(&Tb[w][1][0]);
        int base = 18 * c + 4 * h;
        Xa.w[0] = t32[base];     Xa.w[1] = t32[base + 1];
        Xa.w[2] = t32[base + 2]; Xa.w[3] = t32[base + 3];
        Xb.w[0] = t32[base + 8]; Xb.w[1] = t32[base + 9];
        Xb.w[2] = t32[base + 10]; Xb.w[3] = t32[base + 11];
    }
    zero_acc();
    acc = __builtin_amdgcn_mfma_f32_32x32x16_bf16(Xa.v, W3f[0].v, acc, 0, 0, 0);
    acc = __builtin_amdgcn_mfma_f32_32x32x16_bf16(Xb.v, W3f[1].v, acc, 0, 0, 0);
    if (h == 0) {
        repL[w][64 + c]  = tanh_fast(acc[0] + b3r);
        repL[w][160 + c] = tanh_fast(acc[8] + b3r);
    }
    __syncthreads();

    // ==================== Head ====================
    {
        float a = 0.f;
        #pragma unroll 8
        for (int k2 = 0; k2 < 96; ++k2) {
            int k = h * 96 + k2;
            a += repL[w][k] * lin1W[k * 32 + c];
        }
        a += __shfl_xor(a, 32, 64);
        a += lin1b[c];
        float hr = fmaxf(a, 0.f);
        float pp = hr * lin2W[c];
        #pragma unroll
        for (int off = 16; off > 0; off >>= 1) pp += __shfl_xor(pp, off, 64);
        if (l == 0 && valid) out[b] = pp + lin2b[0];
    }
}

// ---- fallback: device atomics into copy0 of the NCPY-copy layout ----
__global__ __launch_bounds__(256) void build_adj(
    const int* __restrict__ row, const int* __restrict__ col,
    u32* __restrict__ adj, int E)
{
    const int gid = blockIdx.x * blockDim.x + threadIdx.x;
    const int stride = gridDim.x * blockDim.x;
    for (int e = gid; e < E; e += stride) {
        int r = row[e], c = col[e];
        int blk = r >> 5;
        int nibidx = ((r & 31) << 5) | (c & 31);
        size_t addr = (size_t)(blk >> 6) * (8192 * NCPY) + (size_t)(blk & 63) * 128 + (nibidx >> 3);
        atomicAdd(&adj[addr], 1u << ((nibidx & 7) << 2));
    }
}

// ---------------------------------------------------------------------------
extern "C" void kernel_launch(void* const* d_in, const int* in_sizes, int n_in,
                              void* d_out, int out_size, void* d_ws, size_t ws_size,
                              hipStream_t stream)
{
    const float* feats = (const float*)d_in[0];
    const int*   row   = (const int*)d_in[1];
    const int*   col   = (const int*)d_in[2];
    const float* W1    = (const float*)d_in[3];
    const float* b1    = (const float*)d_in[4];
    const float* W2    = (const float*)d_in[5];
    const float* b2    = (const float*)d_in[6];
    const float* W3    = (const float*)d_in[7];
    const float* b3    = (const float*)d_in[8];
    const float* lin1W = (const float*)d_in[9];
    const float* lin1b = (const float*)d_in[10];
    const float* lin2W = (const float*)d_in[11];
    const float* lin2b = (const float*)d_in[12];

    const int N = in_sizes[0] / 4;
    const int E = in_sizes[1];
    const int NB = N / 32;

    const int CH = BATCH;
    const size_t off_ebuf = (size_t)GA * NBKT * 4;                       // count: 1 MB
    const size_t off_adj  = off_ebuf + (size_t)NBKT * GA * CAPC * 2;     // ebuf: 33.5 MB
    const size_t adj_bytes = (size_t)NCPY * NBKT * 8192 * 4;             // 16.8 MB
    const size_t need     = off_adj + adj_bytes;
    const bool fast = (ws_size >= need) && (NB == 8192) && ((E & 3) == 0)
                      && ((size_t)E <= (size_t)GA * BATCH);

    if (fast) {
        u32* count = (u32*)d_ws;
        u16* ebuf  = (u16*)((char*)d_ws + off_ebuf);
        u32* adj   = (u32*)((char*)d_ws + off_adj);
        scatterA<<<GA, 256, 0, stream>>>(row, col, count, ebuf, E, CH);
        countB<<<NCPY * NBKT, 1024, 0, stream>>>(ebuf, count, adj);
        igmc_kernel<<<NB / 4, 256, 0, stream>>>(
            reinterpret_cast<const float4*>(feats), adj, NB,
            W1, b1, W2, b2, W3, b3, lin1W, lin1b, lin2W, lin2b,
            (float*)d_out);
    } else {
        u32* adj = (u32*)d_ws;
        hipMemsetAsync(d_ws, 0, (size_t)NCPY * ((NB + 63) / 64) * 8192 * 4, stream);
        int eblocks = (E + 255) / 256;
        if (eblocks > 2048) eblocks = 2048;
        build_adj<<<eblocks, 256, 0, stream>>>(row, col, adj, E);
        igmc_kernel<<<(NB + 3) / 4, 256, 0, stream>>>(
            reinterpret_cast<const float4*>(feats), adj, NB,
            W1, b1, W2, b2, W3, b3, lin1W, lin1b, lin2W, lin2b,
            (float*)d_out);
    }
}

// Round 19
// 49.493 us; speedup vs baseline: 1.1294x; 1.1294x over previous
//
#include <hip/hip_runtime.h>

typedef __attribute__((ext_vector_type(8))) short bf16x8;
typedef __attribute__((ext_vector_type(16))) float f32x16;
typedef unsigned int u32;
typedef unsigned short u16;

#define GA   1024     // chunks / scatter WGs; 4096 edges each at E=4.2M
#define NBKT 128      // buckets; bucket = 64 consecutive blocks
#define BATCH 4096    // edges per chunk (single batch per WG)
#define CAPC 128      // u16 slots per (chunk,bucket): 4x mean(32); P(ovf)~1e-35
#define NCPY 4        // countB chunk-split copies

union BF8 { bf16x8 v; u16 u[8]; u32 w[4]; };

static __device__ __forceinline__ u16 f2bf(float f) {
    u32 u = __float_as_uint(f);
    return (u16)((u + 0x7FFFu + ((u >> 16) & 1u)) >> 16);   // RNE
}
// packed 2xf32 -> 2xbf16 in ONE instruction (lo in low half)
static __device__ __forceinline__ u32 f2bf2(float lo, float hi) {
    u32 r;
    asm("v_cvt_pk_bf16_f32 %0, %1, %2" : "=v"(r) : "v"(lo), "v"(hi));
    return r;
}
// branchless fast tanh: 8 VALU ops, |err| ~1e-6 (inputs here are |x| <~ 20)
static __device__ __forceinline__ float tanh_fast(float x) {
    float xc = fminf(fmaxf(x, -15.f), 15.f);
    float t = __expf(2.f * xc);
    return (t - 1.f) * __builtin_amdgcn_rcpf(t + 1.f);
}

// ===========================================================================
// Pass 1: compaction scatter into STATIC per-(chunk,bucket) slots.
// (round-12/17 measured-best configuration)
// ===========================================================================
__global__ __launch_bounds__(256) void scatterA(
    const int* __restrict__ row, const int* __restrict__ col,
    u32* __restrict__ count, u16* __restrict__ ebuf, int E, int CH)
{
    __shared__ u32 bcnt[NBKT], bpos[NBKT];
    __shared__ u32 stage[BATCH];
    __shared__ u32 w0s;
    const int t = threadIdx.x, g = blockIdx.x;

    const int beg = g * CH, end = min(E, beg + CH);
    const int nE = end - beg;                       // multiple of 4 (or 0)
    const int4* r4 = reinterpret_cast<const int4*>(row + beg);
    const int4* c4 = reinterpret_cast<const int4*>(col + beg);

    if (t < NBKT) bcnt[t] = 0;
    __syncthreads();

    u32 code[16];
    int rank[16];
    #pragma unroll
    for (int kv = 0; kv < 4; ++kv) {
        int i4 = kv * 256 + t;
        bool v = (i4 * 4) < nE;
        int4 r = v ? r4[i4] : make_int4(0, 0, 0, 0);
        int4 c = v ? c4[i4] : make_int4(0, 0, 0, 0);
        int k0 = kv * 4;
        code[k0 + 0] = v ? (u32)(((r.x >> 5) << 10) | ((r.x & 31) << 5) | (c.x & 31)) : ~0u;
        code[k0 + 1] = v ? (u32)(((r.y >> 5) << 10) | ((r.y & 31) << 5) | (c.y & 31)) : ~0u;
        code[k0 + 2] = v ? (u32)(((r.z >> 5) << 10) | ((r.z & 31) << 5) | (c.z & 31)) : ~0u;
        code[k0 + 3] = v ? (u32)(((r.w >> 5) << 10) | ((r.w & 31) << 5) | (c.w & 31)) : ~0u;
    }
    #pragma unroll
    for (int k = 0; k < 16; ++k)
        rank[k] = (code[k] != ~0u) ? (int)atomicAdd(&bcnt[code[k] >> 16], 1u) : 0;
    __syncthreads();

    // exclusive scan of bcnt over 128 buckets; emit clamped counts
    u32 v_ = (t < NBKT) ? bcnt[t] : 0;
    u32 s = v_;
    #pragma unroll
    for (int off = 1; off < 64; off <<= 1) {
        u32 u_ = __shfl_up(s, off, 64);
        if ((t & 63) >= off) s += u_;
    }
    if (t == 63) w0s = s;
    __syncthreads();
    if (t < NBKT) {
        bpos[t] = s - v_ + ((t >= 64) ? w0s : 0);
        count[g * NBKT + t] = (v_ > CAPC) ? (u32)CAPC : v_;   // coalesced 512 B
    }
    __syncthreads();

    #pragma unroll
    for (int k = 0; k < 16; ++k)
        if (code[k] != ~0u) stage[bpos[code[k] >> 16] + rank[k]] = code[k];
    __syncthreads();

    for (int j = t; j < nE; j += 256) {
        u32 cv = stage[j];
        u32 b = cv >> 16;
        u32 idx = (u32)j - bpos[b];
        if (idx < CAPC)                                   // ~never taken
            ebuf[(b << 17) + ((u32)g << 7) + idx] = (u16)cv;   // run-contiguous
    }
}

// ===========================================================================
// Pass 2: full-bucket nibble-count adjacency, 4-way chunk split (512 WGs).
// (round-12/17 measured-best configuration)
// ===========================================================================
__global__ __launch_bounds__(1024) void countB(
    const u16* __restrict__ ebuf, const u32* __restrict__ count, u32* __restrict__ adj)
{
    __shared__ u32 nib[8192];    // 64 blocks x 128 words = 32 KB
    const int t = threadIdx.x, w = blockIdx.x;
    const int bucket = w >> 2;
    const int g0h = (w & 3) * 256;

    #pragma unroll
    for (int i = t; i < 8192; i += 1024) nib[i] = 0;
    __syncthreads();

    const int wave = t >> 6, lane = t & 63;
    const int g0 = g0h + wave * 16;                 // 16 waves x 16 chunks
    u32 mycnt = (lane < 16) ? count[(g0 + lane) * NBKT + bucket] : 0;
    const u32 base = ((u32)bucket << 17);

    #pragma unroll 4
    for (int it = 0; it < 16; ++it) {
        u32 cnt = (u32)__shfl((int)mycnt, it, 64);  // wave-uniform
        u32 sb = base + ((u32)(g0 + it) << 7);
        u32 lc = ebuf[sb + lane];                   // unconditional, coalesced
        if ((u32)lane < cnt)
            atomicAdd(&nib[lc >> 3], 1u << ((lc & 7) << 2));
        if (cnt > 64) {                             // astronomically rare
            for (u32 i = 64 + (u32)lane; i < cnt; i += 64) {
                u32 lc2 = ebuf[sb + i];
                atomicAdd(&nib[lc2 >> 3], 1u << ((lc2 & 7) << 2));
            }
        }
    }
    __syncthreads();
    u32* dst = adj + (size_t)w * 8192;
    #pragma unroll
    for (int i = t; i < 8192; i += 1024) dst[i] = nib[i];
}

// ===========================================================================
// Kernel 3: 4 subgraphs per 256-thread WG (one wave each), MFMA 32x32x16 bf16.
// (round-17 measured-best configuration)
//   A-frag (assumed): row = l&31, k = 16f + 8*(l>>5) + i
//   B-frag (assumed): col = l&31, k = 16f + 8*(l>>5) + i
//   C/D   (verified): col = l&31, row = (q&3) + 8*(q>>2) + 4*(l>>5)
// ===========================================================================
__global__ __launch_bounds__(256, 6) void igmc_kernel(
    const float4* __restrict__ feats4,
    const u32* __restrict__ adj, int NB,
    const float* __restrict__ W1, const float* __restrict__ B1,
    const float* __restrict__ W2, const float* __restrict__ B2,
    const float* __restrict__ W3, const float* __restrict__ B3,
    const float* __restrict__ lin1W, const float* __restrict__ lin1b,
    const float* __restrict__ lin2W, const float* __restrict__ lin2b,
    float* __restrict__ out)
{
    __shared__ u32 raw[4][128];                       // nibble count words
    __shared__ __align__(16) u16 Tb[4][2][32 * 36];   // bf16 transpose buffers
    __shared__ float nsL[4][32];
    __shared__ __align__(16) float4 fst[4][32];       // feats staging
    __shared__ float repL[4][192];

    const int tid = threadIdx.x;
    const int w = tid >> 6, l = tid & 63, h = l >> 5, c = l & 31;
    const int b = blockIdx.x * 4 + w;
    const bool valid = (b < NB);

    if (valid) {
        const u32* a0 = adj + (size_t)(b >> 6) * (8192 * NCPY) + (size_t)(b & 63) * 128;
        uint2 r0 = *reinterpret_cast<const uint2*>(a0 + 2 * l);
        uint2 r1 = *reinterpret_cast<const uint2*>(a0 + 8192 + 2 * l);
        uint2 r2 = *reinterpret_cast<const uint2*>(a0 + 16384 + 2 * l);
        uint2 r3 = *reinterpret_cast<const uint2*>(a0 + 24576 + 2 * l);
        uint2 rw;
        rw.x = r0.x + r1.x + r2.x + r3.x;             // nibble-wise add, no carry
        rw.y = r0.y + r1.y + r2.y + r3.y;
        *reinterpret_cast<uint2*>(&raw[w][2 * l]) = rw;
        if (h == 0) fst[w][c] = feats4[(size_t)b * 32 + c];
    }
    __syncthreads();

    float cf[16];
    int colsum = 0;
    #pragma unroll
    for (int f = 0; f < 2; ++f)
        #pragma unroll
        for (int i = 0; i < 8; ++i) {
            int u = 16 * f + 8 * h + i;
            u32 word = raw[w][u * 4 + (c >> 3)];
            int v = (word >> ((c & 7) << 2)) & 15;
            cf[f * 8 + i] = (float)v;
            colsum += v;
        }
    colsum += __shfl_xor(colsum, 32, 64);
    const float ndr = rsqrtf(fmaxf((float)colsum, 1.f));

    if (h == 0) {
        u32 r0 = raw[w][4 * c], r1 = raw[w][4 * c + 1];
        u32 r2 = raw[w][4 * c + 2], r3 = raw[w][4 * c + 3];
        const u32 m = 0x0F0F0F0Fu;
        u32 bs = (r0 & m) + ((r0 >> 4) & m) + (r1 & m) + ((r1 >> 4) & m)
               + (r2 & m) + ((r2 >> 4) & m) + (r3 & m) + ((r3 >> 4) & m);
        u32 p2 = (bs & 0x00FF00FFu) + ((bs >> 8) & 0x00FF00FFu);
        u32 s = (p2 + (p2 >> 16)) & 0xFFFFu;
        nsL[w][c] = rsqrtf(fmaxf((float)s, 1.f));
    }
    __syncthreads();

    BF8 Mf[2];
    #pragma unroll
    for (int f = 0; f < 2; ++f)
        #pragma unroll
        for (int j = 0; j < 4; ++j) {
            int u0 = 16 * f + 8 * h + 2 * j;
            Mf[f].w[j] = f2bf2(cf[f * 8 + 2 * j]     * nsL[w][u0]     * ndr,
                               cf[f * 8 + 2 * j + 1] * nsL[w][u0 + 1] * ndr);
        }

    float w1r0 = W1[c], w1r1 = W1[32 + c], w1r2 = W1[64 + c], w1r3 = W1[96 + c];
    const float b1r = B1[c], b2r = B2[c], b3r = B3[c];
    BF8 W2f[2], W3f[2];
    #pragma unroll
    for (int f = 0; f < 2; ++f)
        #pragma unroll
        for (int j = 0; j < 4; ++j) {
            int k0 = 16 * f + 8 * h + 2 * j;
            W2f[f].w[j] = f2bf2(W2[k0 * 32 + c], W2[(k0 + 1) * 32 + c]);
            W3f[f].w[j] = f2bf2(W3[k0 * 32 + c], W3[(k0 + 1) * 32 + c]);
        }

    BF8 Xa, Xb;
    #pragma unroll
    for (int f = 0; f < 2; ++f)
        #pragma unroll
        for (int j = 0; j < 4; ++j) {
            int u0 = 16 * f + 8 * h + 2 * j;
            float4 x0 = fst[w][u0];
            float4 x1 = fst[w][u0 + 1];
            u32 pk = f2bf2(x0.x * w1r0 + x0.y * w1r1 + x0.z * w1r2 + x0.w * w1r3,
                           x1.x * w1r0 + x1.y * w1r1 + x1.z * w1r2 + x1.w * w1r3);
            if (f == 0) Xa.w[j] = pk; else Xb.w[j] = pk;
        }

    f32x16 acc;
    float th[16];
    u32 p[8], q[8];

    auto zero_acc = [&]() {
        #pragma unroll
        for (int j = 0; j < 16; ++j) acc[j] = 0.f;
    };
    auto pack_exchange = [&](BF8& Ra, BF8& Rb) {
        #pragma unroll
        for (int j = 0; j < 8; ++j) p[j] = f2bf2(th[2 * j], th[2 * j + 1]);
        #pragma unroll
        for (int j = 0; j < 8; ++j) q[j] = __shfl_xor((int)p[j], 32, 64);
        Ra.w[0] = h ? q[2] : p[0];  Ra.w[1] = h ? q[3] : p[1];
        Ra.w[2] = h ? p[2] : q[0];  Ra.w[3] = h ? p[3] : q[1];
        Rb.w[0] = h ? q[6] : p[4];  Rb.w[1] = h ? q[7] : p[5];
        Rb.w[2] = h ? p[6] : q[4];  Rb.w[3] = h ? p[7] : q[5];
    };

    // ==================== Layer 1 ====================
    zero_acc();
    acc = __builtin_amdgcn_mfma_f32_32x32x16_bf16(Mf[0].v, Xa.v, acc, 0, 0, 0);
    acc = __builtin_amdgcn_mfma_f32_32x32x16_bf16(Mf[1].v, Xb.v, acc, 0, 0, 0);
    #pragma unroll
    for (int j = 0; j < 16; ++j) th[j] = tanh_fast(acc[j] + b1r);
    if (h == 0) { repL[w][c] = th[0]; repL[w][96 + c] = th[8]; }
    pack_exchange(Xa, Xb);

    // ==================== Layer 2 ====================
    zero_acc();
    acc = __builtin_amdgcn_mfma_f32_32x32x16_bf16(Mf[0].v, Xa.v, acc, 0, 0, 0);
    acc = __builtin_amdgcn_mfma_f32_32x32x16_bf16(Mf[1].v, Xb.v, acc, 0, 0, 0);
    #pragma unroll
    for (int j = 0; j < 16; ++j) {
        int r = (j & 3) + 8 * (j >> 2) + 4 * h;
        Tb[w][0][r * 36 + c] = f2bf(acc[j]);
    }
    __syncthreads();
    {
        const u32* t32 = reinterpret_cast<const u32*>(&Tb[w][0][0]);
        int base = 18 * c + 4 * h;
        Xa.w[0] = t32[base];     Xa.w[1] = t32[base + 1];
        Xa.w[2] = t32[base + 2]; Xa.w[3] = t32[base + 3];
        Xb.w[0] = t32[base + 8]; Xb.w[1] = t32[base + 9];
        Xb.w[2] = t32[base + 10]; Xb.w[3] = t32[base + 11];
    }
    zero_acc();
    acc = __builtin_amdgcn_mfma_f32_32x32x16_bf16(Xa.v, W2f[0].v, acc, 0, 0, 0);
    acc = __builtin_amdgcn_mfma_f32_32x32x16_bf16(Xb.v, W2f[1].v, acc, 0, 0, 0);
    #pragma unroll
    for (int j = 0; j < 16; ++j) th[j] = tanh_fast(acc[j] + b2r);
    if (h == 0) { repL[w][32 + c] = th[0]; repL[w][128 + c] = th[8]; }
    pack_exchange(Xa, Xb);

    // ==================== Layer 3 ====================
    zero_acc();
    acc = __builtin_amdgcn_mfma_f32_32x32x16_bf16(Mf[0].v, Xa.v, acc, 0, 0, 0);
    acc = __builtin_amdgcn_mfma_f32_32x32x16_bf16(Mf[1].v, Xb.v, acc, 0, 0, 0);
    #pragma unroll
    for (int j = 0; j < 16; ++j) {
        int r = (j & 3) + 8 * (j >> 2) + 4 * h;
        Tb[w][1][r * 36 + c] = f2bf(acc[j]);
    }
    __syncthreads();
    {
        const u32* t32 = reinterpret_cast<const u32*>(&Tb[w][1][0]);
        int base = 18 * c + 4 * h;
        Xa.w[0] = t32[base];     Xa.w[1] = t32[base + 1];
        Xa.w[2] = t32[base + 2]; Xa.w[3] = t32[base + 3];
        Xb.w[0] = t32[base + 8]; Xb.w[1] = t32[base + 9];
        Xb.w[2] = t32[base + 10]; Xb.w[3] = t32[base + 11];
    }
    zero_acc();
    acc = __builtin_amdgcn_mfma_f32_32x32x16_bf16(Xa.v, W3f[0].v, acc, 0, 0, 0);
    acc = __builtin_amdgcn_mfma_f32_32x32x16_bf16(Xb.v, W3f[1].v, acc, 0, 0, 0);
    if (h == 0) {
        repL[w][64 + c]  = tanh_fast(acc[0] + b3r);
        repL[w][160 + c] = tanh_fast(acc[8] + b3r);
    }
    __syncthreads();

    // ==================== Head ====================
    {
        float a = 0.f;
        #pragma unroll 8
        for (int k2 = 0; k2 < 96; ++k2) {
            int k = h * 96 + k2;
            a += repL[w][k] * lin1W[k * 32 + c];
        }
        a += __shfl_xor(a, 32, 64);
        a += lin1b[c];
        float hr = fmaxf(a, 0.f);
        float pp = hr * lin2W[c];
        #pragma unroll
        for (int off = 16; off > 0; off >>= 1) pp += __shfl_xor(pp, off, 64);
        if (l == 0 && valid) out[b] = pp + lin2b[0];
    }
}

// ---- fallback: device atomics into copy0 of the NCPY-copy layout ----
__global__ __launch_bounds__(256) void build_adj(
    const int* __restrict__ row, const int* __restrict__ col,
    u32* __restrict__ adj, int E)
{
    const int gid = blockIdx.x * blockDim.x + threadIdx.x;
    const int stride = gridDim.x * blockDim.x;
    for (int e = gid; e < E; e += stride) {
        int r = row[e], c = col[e];
        int blk = r >> 5;
        int nibidx = ((r & 31) << 5) | (c & 31);
        size_t addr = (size_t)(blk >> 6) * (8192 * NCPY) + (size_t)(blk & 63) * 128 + (nibidx >> 3);
        atomicAdd(&adj[addr], 1u << ((nibidx & 7) << 2));
    }
}

// ---------------------------------------------------------------------------
extern "C" void kernel_launch(void* const* d_in, const int* in_sizes, int n_in,
                              void* d_out, int out_size, void* d_ws, size_t ws_size,
                              hipStream_t stream)
{
    const float* feats = (const float*)d_in[0];
    const int*   row   = (const int*)d_in[1];
    const int*   col   = (const int*)d_in[2];
    const float* W1    = (const float*)d_in[3];
    const float* b1    = (const float*)d_in[4];
    const float* W2    = (const float*)d_in[5];
    const float* b2    = (const float*)d_in[6];
    const float* W3    = (const float*)d_in[7];
    const float* b3    = (const float*)d_in[8];
    const float* lin1W = (const float*)d_in[9];
    const float* lin1b = (const float*)d_in[10];
    const float* lin2W = (const float*)d_in[11];
    const float* lin2b = (const float*)d_in[12];

    const int N = in_sizes[0] / 4;
    const int E = in_sizes[1];
    const int NB = N / 32;

    const int CH = BATCH;
    const size_t off_ebuf = (size_t)GA * NBKT * 4;                       // count: 512 KB
    const size_t off_adj  = off_ebuf + (size_t)NBKT * GA * CAPC * 2;     // ebuf: 33.5 MB
    const size_t adj_bytes = (size_t)NCPY * NBKT * 8192 * 4;             // 16.8 MB
    const size_t need     = off_adj + adj_bytes;
    const bool fast = (ws_size >= need) && (NB == 8192) && ((E & 3) == 0)
                      && ((size_t)E <= (size_t)GA * BATCH);

    if (fast) {
        u32* count = (u32*)d_ws;
        u16* ebuf  = (u16*)((char*)d_ws + off_ebuf);
        u32* adj   = (u32*)((char*)d_ws + off_adj);
        scatterA<<<GA, 256, 0, stream>>>(row, col, count, ebuf, E, CH);
        countB<<<NCPY * NBKT, 1024, 0, stream>>>(ebuf, count, adj);
        igmc_kernel<<<NB / 4, 256, 0, stream>>>(
            reinterpret_cast<const float4*>(feats), adj, NB,
            W1, b1, W2, b2, W3, b3, lin1W, lin1b, lin2W, lin2b,
            (float*)d_out);
    } else {
        u32* adj = (u32*)d_ws;
        hipMemsetAsync(d_ws, 0, (size_t)NCPY * ((NB + 63) / 64) * 8192 * 4, stream);
        int eblocks = (E + 255) / 256;
        if (eblocks > 2048) eblocks = 2048;
        build_adj<<<eblocks, 256, 0, stream>>>(row, col, adj, E);
        igmc_kernel<<<(NB + 3) / 4, 256, 0, stream>>>(
            reinterpret_cast<const float4*>(feats), adj, NB,
            W1, b1, W2, b2, W3, b3, lin1W, lin1b, lin2W, lin2b,
            (float*)d_out);
    }
}